// Round 1
// baseline (772.407 us; speedup 1.0000x reference)
//
#include <hip/hip_runtime.h>

constexpr int B_ = 32, T_ = 128, J_ = 24, H_ = 256;
constexpr int BT_ = B_ * T_;        // 4096
constexpr int M_  = BT_ * J_;       // 98304
constexpr float BN_EPS_ = 1e-5f, SLOPE_ = 0.2f;

constexpr size_t OFF_HBUF = 0;
constexpr size_t OFF_BASE = OFF_HBUF + (size_t)M_ * H_;
constexpr size_t OFF_S    = OFF_BASE + (size_t)BT_ * H_;
constexpr size_t OFF_WT   = OFF_S + (size_t)BT_ * H_;
constexpr size_t OFF_HR   = OFF_WT + 768 * 256;
constexpr size_t OFF_BNSC = OFF_HR + (size_t)B_ * H_;
constexpr size_t OFF_BNSH = OFF_BNSC + 256;

__global__ __launch_bounds__(256) void k_misc(
    const float* __restrict__ tau, const float* __restrict__ w_t1,
    const float* __restrict__ b_t1, const float* __restrict__ w_conv,
    const float* __restrict__ gamma, const float* __restrict__ beta,
    const float* __restrict__ mean, const float* __restrict__ var,
    float* __restrict__ s, float* __restrict__ wt,
    float* __restrict__ bnsc, float* __restrict__ bnsh) {
  int bid = blockIdx.x, tid = threadIdx.x;
  float tv = tau[bid];
  float v = tv * w_t1[tid] + b_t1[tid];
  s[bid * H_ + tid] = v / (1.f + expf(-v));
  if (bid < 768) {
    int k = bid >> 8, i = bid & 255;
    wt[bid * H_ + tid] = w_conv[tid * 768 + i * 3 + k];
  }
  if (bid == 0) {
    float sc = gamma[tid] * rsqrtf(var[tid] + BN_EPS_);
    bnsc[tid] = sc;
    bnsh[tid] = beta[tid] - mean[tid] * sc;
  }
}

__global__ __launch_bounds__(256) void k_hr(
    const float* __restrict__ hn, const float* __restrict__ w_radar,
    const float* __restrict__ b_radar, float* __restrict__ hr) {
  __shared__ float hs[H_];
  int b = blockIdx.x, c = threadIdx.x;
  hs[c] = hn[b * H_ + c];
  __syncthreads();
  float acc = b_radar[c];
  for (int k = 0; k < H_; ++k) acc += hs[k] * w_radar[k * H_ + c];
  hr[b * H_ + c] = acc;
}

__global__ __launch_bounds__(256) void k_base(
    const float* __restrict__ s, const float* __restrict__ z,
    const float* __restrict__ w_t2, const float* __restrict__ w_radar,
    const float* __restrict__ b_t2, const float* __restrict__ b_radar,
    const float* __restrict__ hr, float* __restrict__ basep) {
  __shared__ float As[16][40];
  __shared__ float Bs[16][128];
  int bm = blockIdx.x & 127, bn = blockIdx.x >> 7;
  int row0 = bm * 32, col0 = bn * 128;
  int tid = threadIdx.x, ty = tid >> 5, tx = tid & 31;
  float acc[4][4] = {};
  for (int ck = 0; ck < 32; ++ck) {
    const float* A = (ck < 16) ? s : z;
    const float* W = (ck < 16) ? w_t2 : w_radar;
    int k0 = (ck & 15) * 16;
    if (tid < 128) {
      int r = tid >> 2, q = tid & 3;
      float4 v = *(const float4*)&A[(row0 + r) * H_ + k0 + q * 4];
      As[q * 4 + 0][r] = v.x; As[q * 4 + 1][r] = v.y;
      As[q * 4 + 2][r] = v.z; As[q * 4 + 3][r] = v.w;
    }
#pragma unroll
    for (int p = 0; p < 2; ++p) {
      int idx = tid + p * 256;
      int br = idx >> 5, c4 = idx & 31;
      *(float4*)&Bs[br][c4 * 4] = *(const float4*)&W[(k0 + br) * H_ + col0 + c4 * 4];
    }
    __syncthreads();
#pragma unroll
    for (int kk = 0; kk < 16; ++kk) {
      float4 av = *(const float4*)&As[kk][ty * 4];
      float4 bv = *(const float4*)&Bs[kk][tx * 4];
      float a[4] = {av.x, av.y, av.z, av.w};
      float b[4] = {bv.x, bv.y, bv.z, bv.w};
#pragma unroll
      for (int i = 0; i < 4; ++i)
#pragma unroll
        for (int j = 0; j < 4; ++j) acc[i][j] += a[i] * b[j];
    }
    __syncthreads();
  }
#pragma unroll
  for (int i = 0; i < 4; ++i) {
    int bt = row0 + ty * 4 + i;
    int b = bt >> 7;
    int c = col0 + tx * 4;
    float4 o;
    o.x = acc[i][0] + b_t2[c + 0] + b_radar[c + 0] + hr[b * H_ + c + 0];
    o.y = acc[i][1] + b_t2[c + 1] + b_radar[c + 1] + hr[b * H_ + c + 1];
    o.z = acc[i][2] + b_t2[c + 2] + b_radar[c + 2] + hr[b * H_ + c + 2];
    o.w = acc[i][3] + b_t2[c + 3] + b_radar[c + 3] + hr[b * H_ + c + 3];
    *(float4*)&basep[bt * H_ + c] = o;
  }
}

__global__ __launch_bounds__(256) void k_hg(
    const float* __restrict__ xt, const float* __restrict__ basep,
    const float* __restrict__ adj, const float* __restrict__ w_joint,
    const float* __restrict__ b_joint, float* __restrict__ hbuf) {
  __shared__ float xs[J_ * 3];
  __shared__ float hsl[J_][H_];
  int bt = blockIdx.x, c = threadIdx.x;
  if (c < J_ * 3) xs[c] = xt[bt * (J_ * 3) + c];
  __syncthreads();
  float wj0 = w_joint[c], wj1 = w_joint[H_ + c], wj2 = w_joint[2 * H_ + c];
  float hb = b_joint[c] + basep[bt * H_ + c];
#pragma unroll
  for (int j = 0; j < J_; ++j)
    hsl[j][c] = xs[j * 3] * wj0 + xs[j * 3 + 1] * wj1 + xs[j * 3 + 2] * wj2 + hb;
  __syncthreads();
  float acc[J_];
#pragma unroll
  for (int j = 0; j < J_; ++j) acc[j] = 0.f;
  for (int kp = 0; kp < J_; ++kp) {
    float hv = hsl[kp][c];
#pragma unroll
    for (int j = 0; j < J_; ++j) acc[j] += adj[j * J_ + kp] * hv;
  }
#pragma unroll
  for (int j = 0; j < J_; ++j) hbuf[(size_t)(bt * J_ + j) * H_ + c] = acc[j];
}

__global__ __launch_bounds__(256) void k_gcn(
    const float* __restrict__ w_gcn, const float* __restrict__ b_gcn,
    const float* __restrict__ xt, const float* __restrict__ basep,
    const float* __restrict__ w_joint, const float* __restrict__ b_joint,
    float* __restrict__ hbuf) {
  __shared__ float As[16][68];
  __shared__ float Bs[16][256];
  int r0 = blockIdx.x * 64;
  int tid = threadIdx.x, ty = tid >> 5, tx = tid & 31;
  float acc[8][8] = {};
  for (int ck = 0; ck < 16; ++ck) {
    int k0 = ck * 16;
    {
      int r = tid >> 2, q = tid & 3;
      float4 v = *(const float4*)&hbuf[(size_t)(r0 + r) * H_ + k0 + q * 4];
      As[q * 4 + 0][r] = v.x; As[q * 4 + 1][r] = v.y;
      As[q * 4 + 2][r] = v.z; As[q * 4 + 3][r] = v.w;
    }
#pragma unroll
    for (int p = 0; p < 4; ++p) {
      int idx = tid + p * 256;
      int br = idx >> 6, c4 = idx & 63;
      *(float4*)&Bs[br][c4 * 4] = *(const float4*)&w_gcn[(k0 + br) * H_ + c4 * 4];
    }
    __syncthreads();
#pragma unroll
    for (int kk = 0; kk < 16; ++kk) {
      float a[8], b[8];
      *(float4*)&a[0] = *(const float4*)&As[kk][ty * 8];
      *(float4*)&a[4] = *(const float4*)&As[kk][ty * 8 + 4];
      *(float4*)&b[0] = *(const float4*)&Bs[kk][tx * 4];
      *(float4*)&b[4] = *(const float4*)&Bs[kk][tx * 4 + 128];
#pragma unroll
      for (int i = 0; i < 8; ++i)
#pragma unroll
        for (int j = 0; j < 8; ++j) acc[i][j] += a[i] * b[j];
    }
    __syncthreads();
  }
  float wj[3][8], bj8[8], bg8[8];
#pragma unroll
  for (int cc = 0; cc < 8; ++cc) {
    int c = (cc < 4) ? tx * 4 + cc : 128 + tx * 4 + cc - 4;
    wj[0][cc] = w_joint[c]; wj[1][cc] = w_joint[H_ + c]; wj[2][cc] = w_joint[2 * H_ + c];
    bj8[cc] = b_joint[c]; bg8[cc] = b_gcn[c];
  }
#pragma unroll
  for (int i = 0; i < 8; ++i) {
    int row = r0 + ty * 8 + i;
    int bt = row / J_;
    float x0 = xt[row * 3], x1 = xt[row * 3 + 1], x2 = xt[row * 3 + 2];
    float out[8];
#pragma unroll
    for (int cc = 0; cc < 8; ++cc) {
      int c = (cc < 4) ? tx * 4 + cc : 128 + tx * 4 + cc - 4;
      float h = x0 * wj[0][cc] + x1 * wj[1][cc] + x2 * wj[2][cc] + bj8[cc] + basep[bt * H_ + c];
      float g = acc[i][cc] + bg8[cc];
      out[cc] = h + (g > 0.f ? g : 0.f);
    }
    *(float4*)&hbuf[(size_t)row * H_ + tx * 4] = make_float4(out[0], out[1], out[2], out[3]);
    *(float4*)&hbuf[(size_t)row * H_ + 128 + tx * 4] = make_float4(out[4], out[5], out[6], out[7]);
  }
}

__global__ __launch_bounds__(256) void k_conv(
    const float* __restrict__ wt, const float* __restrict__ b_conv,
    const float* __restrict__ bnsc, const float* __restrict__ bnsh,
    const float* __restrict__ w_out, const float* __restrict__ b_out,
    const float* __restrict__ hbuf, float* __restrict__ vout) {
  __shared__ float As[16][68];
  __shared__ float Bs[16][256];
  int r0 = blockIdx.x * 64;
  int tid = threadIdx.x, ty = tid >> 5, tx = tid & 31;
  int sr = tid >> 2, sq = tid & 3;
  int srow = r0 + sr;
  int st = (srow / J_) & (T_ - 1);
  float acc[8][8] = {};
  for (int ck = 0; ck < 48; ++ck) {
    int tap = ck >> 4;
    int i0 = (ck & 15) * 16;
    int shift = (tap - 1) * J_;
    float4 v = make_float4(0.f, 0.f, 0.f, 0.f);
    if ((unsigned)(st + tap - 1) < (unsigned)T_)
      v = *(const float4*)&hbuf[(size_t)(srow + shift) * H_ + i0 + sq * 4];
    As[sq * 4 + 0][sr] = v.x; As[sq * 4 + 1][sr] = v.y;
    As[sq * 4 + 2][sr] = v.z; As[sq * 4 + 3][sr] = v.w;
#pragma unroll
    for (int p = 0; p < 4; ++p) {
      int idx = tid + p * 256;
      int br = idx >> 6, c4 = idx & 63;
      *(float4*)&Bs[br][c4 * 4] = *(const float4*)&wt[(size_t)(ck * 16 + br) * H_ + c4 * 4];
    }
    __syncthreads();
#pragma unroll
    for (int kk = 0; kk < 16; ++kk) {
      float a[8], b[8];
      *(float4*)&a[0] = *(const float4*)&As[kk][ty * 8];
      *(float4*)&a[4] = *(const float4*)&As[kk][ty * 8 + 4];
      *(float4*)&b[0] = *(const float4*)&Bs[kk][tx * 4];
      *(float4*)&b[4] = *(const float4*)&Bs[kk][tx * 4 + 128];
#pragma unroll
      for (int i = 0; i < 8; ++i)
#pragma unroll
        for (int j = 0; j < 8; ++j) acc[i][j] += a[i] * b[j];
    }
    __syncthreads();
  }
  float bc[8], sc[8], sh[8], w0[8], w1[8], w2[8];
#pragma unroll
  for (int cc = 0; cc < 8; ++cc) {
    int o = (cc < 4) ? tx * 4 + cc : 128 + tx * 4 + cc - 4;
    bc[cc] = b_conv[o]; sc[cc] = bnsc[o]; sh[cc] = bnsh[o];
    w0[cc] = w_out[o * 3]; w1[cc] = w_out[o * 3 + 1]; w2[cc] = w_out[o * 3 + 2];
  }
  float bo0 = b_out[0], bo1 = b_out[1], bo2 = b_out[2];
#pragma unroll
  for (int i = 0; i < 8; ++i) {
    int row = r0 + ty * 8 + i;
    float pv0 = 0.f, pv1 = 0.f, pv2 = 0.f;
#pragma unroll
    for (int cc = 0; cc < 8; ++cc) {
      float h = acc[i][cc] + bc[cc];
      h = h * sc[cc] + sh[cc];
      h = (h >= 0.f) ? h : SLOPE_ * h;
      pv0 += h * w0[cc]; pv1 += h * w1[cc]; pv2 += h * w2[cc];
    }
#pragma unroll
    for (int m = 16; m >= 1; m >>= 1) {
      pv0 += __shfl_xor(pv0, m);
      pv1 += __shfl_xor(pv1, m);
      pv2 += __shfl_xor(pv2, m);
    }
    if (tx == 0) {
      vout[row * 3 + 0] = pv0 + bo0;
      vout[row * 3 + 1] = pv1 + bo1;
      vout[row * 3 + 2] = pv2 + bo2;
    }
  }
}

extern "C" void kernel_launch(void* const* d_in, const int* in_sizes, int n_in,
                              void* d_out, int out_size, void* d_ws, size_t ws_size,
                              hipStream_t stream) {
  const float* xt      = (const float*)d_in[0];
  const float* tau     = (const float*)d_in[1];
  const float* z       = (const float*)d_in[2];
  const float* hn      = (const float*)d_in[3];
  const float* adj     = (const float*)d_in[4];
  const float* w_joint = (const float*)d_in[5];
  const float* b_joint = (const float*)d_in[6];
  const float* w_t1    = (const float*)d_in[7];
  const float* b_t1    = (const float*)d_in[8];
  const float* w_t2    = (const float*)d_in[9];
  const float* b_t2    = (const float*)d_in[10];
  const float* w_radar = (const float*)d_in[11];
  const float* b_radar = (const float*)d_in[12];
  const float* w_gcn   = (const float*)d_in[13];
  const float* b_gcn   = (const float*)d_in[14];
  const float* w_conv  = (const float*)d_in[15];
  const float* b_conv  = (const float*)d_in[16];
  const float* gamma   = (const float*)d_in[17];
  const float* beta    = (const float*)d_in[18];
  const float* mean    = (const float*)d_in[19];
  const float* var     = (const float*)d_in[20];
  const float* w_out   = (const float*)d_in[21];
  const float* b_out   = (const float*)d_in[22];

  float* ws   = (float*)d_ws;
  float* hbuf = ws + OFF_HBUF;
  float* base = ws + OFF_BASE;
  float* s    = ws + OFF_S;
  float* wtb  = ws + OFF_WT;
  float* hr   = ws + OFF_HR;
  float* bnsc = ws + OFF_BNSC;
  float* bnsh = ws + OFF_BNSH;
  float* vout = (float*)d_out;

  hipLaunchKernelGGL(k_misc, dim3(BT_), dim3(256), 0, stream,
                     tau, w_t1, b_t1, w_conv, gamma, beta, mean, var, s, wtb, bnsc, bnsh);
  hipLaunchKernelGGL(k_hr, dim3(B_), dim3(256), 0, stream, hn, w_radar, b_radar, hr);
  hipLaunchKernelGGL(k_base, dim3(256), dim3(256), 0, stream,
                     s, z, w_t2, w_radar, b_t2, b_radar, hr, base);
  hipLaunchKernelGGL(k_hg, dim3(BT_), dim3(256), 0, stream,
                     xt, base, adj, w_joint, b_joint, hbuf);
  hipLaunchKernelGGL(k_gcn, dim3(M_ / 64), dim3(256), 0, stream,
                     w_gcn, b_gcn, xt, base, w_joint, b_joint, hbuf);
  hipLaunchKernelGGL(k_conv, dim3(M_ / 64), dim3(256), 0, stream,
                     wtb, b_conv, bnsc, bnsh, w_out, b_out, hbuf, vout);
}

// Round 2
// 470.183 us; speedup vs baseline: 1.6428x; 1.6428x over previous
//
#include <hip/hip_runtime.h>

typedef __attribute__((ext_vector_type(8))) short short8v;
typedef __attribute__((ext_vector_type(4))) float float4v;
typedef unsigned short u16;

constexpr int B_ = 32, T_ = 128, J_ = 24, H_ = 256;
constexpr int BT_ = B_ * T_;   // 4096
constexpr int M_  = BT_ * J_;  // 98304
constexpr float BN_EPS_ = 1e-5f, SLOPE_ = 0.2f;

// ---- workspace byte offsets ----
constexpr size_t OB_HGB  = 0;                          // bf16 [M][256] hg -> h2 (in place)
constexpr size_t OB_HB   = OB_HGB + (size_t)M_ * H_ * 2;   // bf16 [M][256] residual h
constexpr size_t OB_BASE = OB_HB  + (size_t)M_ * H_ * 2;   // f32 [BT][256]
constexpr size_t OB_S    = OB_BASE + (size_t)BT_ * H_ * 4; // f32 [BT][256]
constexpr size_t OB_WTF  = OB_S + (size_t)BT_ * H_ * 4;    // bf16 768*256 fragment-packed
constexpr size_t OB_WGF  = OB_WTF + 768 * 256 * 2;         // bf16 256*256 fragment-packed
constexpr size_t OB_HR   = OB_WGF + 256 * 256 * 2;         // f32 [32][256]
constexpr size_t OB_BNSC = OB_HR + (size_t)B_ * H_ * 4;    // f32 256
constexpr size_t OB_BNSH = OB_BNSC + 256 * 4;              // f32 256

__device__ __forceinline__ u16 f2b(float f) {
  union { float f; unsigned u; } v; v.f = f;
  return (u16)((v.u + 0x7fffu + ((v.u >> 16) & 1u)) >> 16);
}
__device__ __forceinline__ float b2f(u16 u) {
  union { unsigned u; float f; } v; v.u = ((unsigned)u) << 16; return v.f;
}

// ---------------------------------------------------------------- prep: silu(tau w1+b1), BN constants
__global__ __launch_bounds__(256) void k_misc(
    const float* __restrict__ tau, const float* __restrict__ w_t1,
    const float* __restrict__ b_t1, const float* __restrict__ gamma,
    const float* __restrict__ beta, const float* __restrict__ mean,
    const float* __restrict__ var, float* __restrict__ s,
    float* __restrict__ bnsc, float* __restrict__ bnsh) {
  int bid = blockIdx.x, tid = threadIdx.x;
  float tv = tau[bid];
  float v = tv * w_t1[tid] + b_t1[tid];
  s[bid * H_ + tid] = v / (1.f + expf(-v));
  if (bid == 0) {
    float sc = gamma[tid] * rsqrtf(var[tid] + BN_EPS_);
    bnsc[tid] = sc;
    bnsh[tid] = beta[tid] - mean[tid] * sc;
  }
}

// ---------------------------------------------------------------- pack conv/gcn weights into MFMA B-fragment order (bf16)
// layout: frag (kb,nblk): lane l, elem j -> W[kb*32 + (l>>4)*8 + j][nblk*16 + (l&15)]
__global__ __launch_bounds__(64) void k_pack(
    const float* __restrict__ w_conv, const float* __restrict__ w_gcn,
    u16* __restrict__ wtf, u16* __restrict__ wgf) {
  int bid = blockIdx.x, l = threadIdx.x;
  int col = (l & 15), kbase = (l >> 4) * 8;
  if (bid < 384) {  // wtf: K=768 (24 kb), k_lin = tap*256 + i, val = w_conv[o*768 + i*3 + tap]
    int kb = bid >> 4, nblk = bid & 15;
    int o = nblk * 16 + col;
    u16* dst = wtf + (size_t)bid * 512 + l * 8;
#pragma unroll
    for (int j = 0; j < 8; ++j) {
      int k = kb * 32 + kbase + j;
      int tap = k >> 8, i = k & 255;
      dst[j] = f2b(w_conv[o * 768 + i * 3 + tap]);
    }
  } else {          // wgf: K=256 (8 kb), val = w_gcn[k*256 + o]
    int b2 = bid - 384;
    int kb = b2 >> 4, nblk = b2 & 15;
    int o = nblk * 16 + col;
    u16* dst = wgf + (size_t)b2 * 512 + l * 8;
#pragma unroll
    for (int j = 0; j < 8; ++j) {
      int k = kb * 32 + kbase + j;
      dst[j] = f2b(w_gcn[k * 256 + o]);
    }
  }
}

// ---------------------------------------------------------------- hr = h_n @ w_radar + b_radar
__global__ __launch_bounds__(256) void k_hr(
    const float* __restrict__ hn, const float* __restrict__ w_radar,
    const float* __restrict__ b_radar, float* __restrict__ hr) {
  __shared__ float hs[H_];
  int b = blockIdx.x, c = threadIdx.x;
  hs[c] = hn[b * H_ + c];
  __syncthreads();
  float acc = b_radar[c];
  for (int k = 0; k < H_; ++k) acc += hs[k] * w_radar[k * H_ + c];
  hr[b * H_ + c] = acc;
}

// ---------------------------------------------------------------- base = s@w_t2 + z@w_radar + b_t2 + b_radar + hr[b]  (fp32)
__global__ __launch_bounds__(256) void k_base(
    const float* __restrict__ s, const float* __restrict__ z,
    const float* __restrict__ w_t2, const float* __restrict__ w_radar,
    const float* __restrict__ b_t2, const float* __restrict__ b_radar,
    const float* __restrict__ hr, float* __restrict__ basep) {
  __shared__ float As[16][40];
  __shared__ float Bs[16][128];
  int bm = blockIdx.x & 127, bn = blockIdx.x >> 7;
  int row0 = bm * 32, col0 = bn * 128;
  int tid = threadIdx.x, ty = tid >> 5, tx = tid & 31;
  float acc[4][4] = {};
  for (int ck = 0; ck < 32; ++ck) {
    const float* A = (ck < 16) ? s : z;
    const float* W = (ck < 16) ? w_t2 : w_radar;
    int k0 = (ck & 15) * 16;
    if (tid < 128) {
      int r = tid >> 2, q = tid & 3;
      float4 v = *(const float4*)&A[(row0 + r) * H_ + k0 + q * 4];
      As[q * 4 + 0][r] = v.x; As[q * 4 + 1][r] = v.y;
      As[q * 4 + 2][r] = v.z; As[q * 4 + 3][r] = v.w;
    }
#pragma unroll
    for (int p = 0; p < 2; ++p) {
      int idx = tid + p * 256;
      int br = idx >> 5, c4 = idx & 31;
      *(float4*)&Bs[br][c4 * 4] = *(const float4*)&W[(k0 + br) * H_ + col0 + c4 * 4];
    }
    __syncthreads();
#pragma unroll
    for (int kk = 0; kk < 16; ++kk) {
      float4 av = *(const float4*)&As[kk][ty * 4];
      float4 bv = *(const float4*)&Bs[kk][tx * 4];
      float a[4] = {av.x, av.y, av.z, av.w};
      float b[4] = {bv.x, bv.y, bv.z, bv.w};
#pragma unroll
      for (int i = 0; i < 4; ++i)
#pragma unroll
        for (int j = 0; j < 4; ++j) acc[i][j] += a[i] * b[j];
    }
    __syncthreads();
  }
#pragma unroll
  for (int i = 0; i < 4; ++i) {
    int bt = row0 + ty * 4 + i;
    int b = bt >> 7;
    int c = col0 + tx * 4;
    float4 o;
    o.x = acc[i][0] + b_t2[c + 0] + b_radar[c + 0] + hr[b * H_ + c + 0];
    o.y = acc[i][1] + b_t2[c + 1] + b_radar[c + 1] + hr[b * H_ + c + 1];
    o.z = acc[i][2] + b_t2[c + 2] + b_radar[c + 2] + hr[b * H_ + c + 2];
    o.w = acc[i][3] + b_t2[c + 3] + b_radar[c + 3] + hr[b * H_ + c + 3];
    *(float4*)&basep[bt * H_ + c] = o;
  }
}

// ---------------------------------------------------------------- h (bf16) and hg = adj@h (bf16)
__global__ __launch_bounds__(256) void k_hg(
    const float* __restrict__ xt, const float* __restrict__ basep,
    const float* __restrict__ adj, const float* __restrict__ w_joint,
    const float* __restrict__ b_joint, u16* __restrict__ hgb,
    u16* __restrict__ hb) {
  __shared__ float xs[J_ * 3];
  int bt = blockIdx.x, c = threadIdx.x;
  if (c < J_ * 3) xs[c] = xt[bt * (J_ * 3) + c];
  __syncthreads();
  float wj0 = w_joint[c], wj1 = w_joint[H_ + c], wj2 = w_joint[2 * H_ + c];
  float hbase = b_joint[c] + basep[bt * H_ + c];
  float hv[J_];
#pragma unroll
  for (int j = 0; j < J_; ++j) {
    hv[j] = xs[j * 3] * wj0 + xs[j * 3 + 1] * wj1 + xs[j * 3 + 2] * wj2 + hbase;
    hb[(size_t)(bt * J_ + j) * H_ + c] = f2b(hv[j]);
  }
  float acc[J_];
#pragma unroll
  for (int j = 0; j < J_; ++j) acc[j] = 0.f;
  for (int kp = 0; kp < J_; ++kp) {
    float hvk = hv[kp];
#pragma unroll
    for (int j = 0; j < J_; ++j) acc[j] += adj[j * J_ + kp] * hvk;
  }
#pragma unroll
  for (int j = 0; j < J_; ++j) hgb[(size_t)(bt * J_ + j) * H_ + c] = f2b(acc[j]);
}

// ---------------------------------------------------------------- MFMA GCN: h2 = h + relu(hg@w_gcn + b), in place over hgb
__global__ __launch_bounds__(256) void k_gcn2(
    const u16* __restrict__ wgf, const float* __restrict__ b_gcn,
    const u16* __restrict__ hb, u16* __restrict__ hgb) {
  __shared__ u16 Bl[8192];  // 16 KB: one K-step of all 16 n-frags
  int tid = threadIdx.x;
  int l = tid & 63, w = tid >> 6;
  int wm = w & 1, wn = w >> 1;
  int r0 = blockIdx.x * 64;
  float4v z4 = {0.f, 0.f, 0.f, 0.f};
  float4v acc[2][8];
#pragma unroll
  for (int mi = 0; mi < 2; ++mi)
#pragma unroll
    for (int ni = 0; ni < 8; ++ni) acc[mi][ni] = z4;

  const float4* wsrc = (const float4*)wgf;
  float4* Bl4 = (float4*)Bl;
  float4 stg[4];
#pragma unroll
  for (int p = 0; p < 4; ++p) stg[p] = wsrc[p * 256 + tid];

  int arow = r0 + wm * 32 + (l & 15);
  int kof0 = (l >> 4) * 8;
  short8v acur0, acur1;
  short8v anx0 = *(const short8v*)&hgb[(size_t)arow * 256 + kof0];
  short8v anx1 = *(const short8v*)&hgb[(size_t)(arow + 16) * 256 + kof0];

  for (int kb = 0; kb < 8; ++kb) {
    __syncthreads();
#pragma unroll
    for (int p = 0; p < 4; ++p) Bl4[p * 256 + tid] = stg[p];
    __syncthreads();
    if (kb < 7) {
#pragma unroll
      for (int p = 0; p < 4; ++p) stg[p] = wsrc[(kb + 1) * 1024 + p * 256 + tid];
    }
    acur0 = anx0; acur1 = anx1;
    if (kb < 7) {
      int kof = (kb + 1) * 32 + kof0;
      anx0 = *(const short8v*)&hgb[(size_t)arow * 256 + kof];
      anx1 = *(const short8v*)&hgb[(size_t)(arow + 16) * 256 + kof];
    }
#pragma unroll
    for (int ni = 0; ni < 8; ++ni) {
      short8v bf = *(const short8v*)&Bl[((wn * 8 + ni) * 64 + l) * 8];
      acc[0][ni] = __builtin_amdgcn_mfma_f32_16x16x32_bf16(acur0, bf, acc[0][ni], 0, 0, 0);
      acc[1][ni] = __builtin_amdgcn_mfma_f32_16x16x32_bf16(acur1, bf, acc[1][ni], 0, 0, 0);
    }
  }
  __syncthreads();  // in-place: all A reads done before epilogue writes
  int g = l >> 4;
#pragma unroll
  for (int mi = 0; mi < 2; ++mi)
#pragma unroll
    for (int ni = 0; ni < 8; ++ni) {
      int col = wn * 128 + ni * 16 + (l & 15);
      float bg = b_gcn[col];
#pragma unroll
      for (int r = 0; r < 4; ++r) {
        int row = r0 + wm * 32 + mi * 16 + g * 4 + r;
        float hres = b2f(hb[(size_t)row * 256 + col]);
        float gv = acc[mi][ni][r] + bg;
        hgb[(size_t)row * 256 + col] = f2b(hres + (gv > 0.f ? gv : 0.f));
      }
    }
}

// ---------------------------------------------------------------- MFMA conv(K=3) + BN + leaky + out-proj fused
__global__ __launch_bounds__(256) void k_conv2(
    const u16* __restrict__ wtf, const float* __restrict__ b_conv,
    const float* __restrict__ bnsc, const float* __restrict__ bnsh,
    const float* __restrict__ w_out, const float* __restrict__ b_out,
    const u16* __restrict__ h2b, float* __restrict__ vout) {
  __shared__ u16 Bl[8192];
  __shared__ float outp[64][3];
  int tid = threadIdx.x;
  int l = tid & 63, w = tid >> 6;
  int wm = w & 1, wn = w >> 1;
  int r0 = blockIdx.x * 64;
  float4v z4 = {0.f, 0.f, 0.f, 0.f};
  float4v acc[2][8];
#pragma unroll
  for (int mi = 0; mi < 2; ++mi)
#pragma unroll
    for (int ni = 0; ni < 8; ++ni) acc[mi][ni] = z4;

  const float4* wsrc = (const float4*)wtf;
  float4* Bl4 = (float4*)Bl;
  float4 stg[4];
#pragma unroll
  for (int p = 0; p < 4; ++p) stg[p] = wsrc[p * 256 + tid];

  int arow = r0 + wm * 32 + (l & 15);
  int kof0 = (l >> 4) * 8;
  auto aload = [&](int kb, int mi) -> short8v {
    int tap = kb >> 3;
    int rr = arow + mi * 16;
    int t = (rr / 24) & 127;
    short8v z = {0, 0, 0, 0, 0, 0, 0, 0};
    if ((unsigned)(t + tap - 1) >= 128u) return z;
    int i0 = (kb & 7) * 32 + kof0;
    return *(const short8v*)&h2b[(size_t)(rr + (tap - 1) * 24) * 256 + i0];
  };
  short8v acur0, acur1;
  short8v anx0 = aload(0, 0);
  short8v anx1 = aload(0, 1);

  for (int kb = 0; kb < 24; ++kb) {
    __syncthreads();
#pragma unroll
    for (int p = 0; p < 4; ++p) Bl4[p * 256 + tid] = stg[p];
    __syncthreads();
    if (kb < 23) {
#pragma unroll
      for (int p = 0; p < 4; ++p) stg[p] = wsrc[(kb + 1) * 1024 + p * 256 + tid];
    }
    acur0 = anx0; acur1 = anx1;
    if (kb < 23) {
      anx0 = aload(kb + 1, 0);
      anx1 = aload(kb + 1, 1);
    }
#pragma unroll
    for (int ni = 0; ni < 8; ++ni) {
      short8v bf = *(const short8v*)&Bl[((wn * 8 + ni) * 64 + l) * 8];
      acc[0][ni] = __builtin_amdgcn_mfma_f32_16x16x32_bf16(acur0, bf, acc[0][ni], 0, 0, 0);
      acc[1][ni] = __builtin_amdgcn_mfma_f32_16x16x32_bf16(acur1, bf, acc[1][ni], 0, 0, 0);
    }
  }
  // ---- epilogue: BN + leaky + out-proj, reduce 256 cols -> 3
  float pv[2][4][3] = {};
#pragma unroll
  for (int ni = 0; ni < 8; ++ni) {
    int col = wn * 128 + ni * 16 + (l & 15);
    float bc = b_conv[col], sc = bnsc[col], sh = bnsh[col];
    float w0 = w_out[col * 3], w1 = w_out[col * 3 + 1], w2 = w_out[col * 3 + 2];
#pragma unroll
    for (int mi = 0; mi < 2; ++mi)
#pragma unroll
      for (int r = 0; r < 4; ++r) {
        float hvv = acc[mi][ni][r] + bc;
        hvv = hvv * sc + sh;
        hvv = (hvv >= 0.f) ? hvv : SLOPE_ * hvv;
        pv[mi][r][0] += hvv * w0;
        pv[mi][r][1] += hvv * w1;
        pv[mi][r][2] += hvv * w2;
      }
  }
#pragma unroll
  for (int mi = 0; mi < 2; ++mi)
#pragma unroll
    for (int r = 0; r < 4; ++r)
#pragma unroll
      for (int c = 0; c < 3; ++c) {
        float v = pv[mi][r][c];
        v += __shfl_xor(v, 1);
        v += __shfl_xor(v, 2);
        v += __shfl_xor(v, 4);
        v += __shfl_xor(v, 8);
        pv[mi][r][c] = v;
      }
  int g = l >> 4;
  if (wn == 1 && (l & 15) == 0) {
#pragma unroll
    for (int mi = 0; mi < 2; ++mi)
#pragma unroll
      for (int r = 0; r < 4; ++r) {
        int rl = wm * 32 + mi * 16 + g * 4 + r;
        outp[rl][0] = pv[mi][r][0];
        outp[rl][1] = pv[mi][r][1];
        outp[rl][2] = pv[mi][r][2];
      }
  }
  __syncthreads();
  if (wn == 0 && (l & 15) == 0) {
#pragma unroll
    for (int mi = 0; mi < 2; ++mi)
#pragma unroll
      for (int r = 0; r < 4; ++r) {
        int rl = wm * 32 + mi * 16 + g * 4 + r;
        size_t row = (size_t)(r0 + rl);
        vout[row * 3 + 0] = pv[mi][r][0] + outp[rl][0] + b_out[0];
        vout[row * 3 + 1] = pv[mi][r][1] + outp[rl][1] + b_out[1];
        vout[row * 3 + 2] = pv[mi][r][2] + outp[rl][2] + b_out[2];
      }
  }
}

extern "C" void kernel_launch(void* const* d_in, const int* in_sizes, int n_in,
                              void* d_out, int out_size, void* d_ws, size_t ws_size,
                              hipStream_t stream) {
  (void)in_sizes; (void)n_in; (void)out_size; (void)ws_size;
  const float* xt      = (const float*)d_in[0];
  const float* tau     = (const float*)d_in[1];
  const float* z       = (const float*)d_in[2];
  const float* hn      = (const float*)d_in[3];
  const float* adj     = (const float*)d_in[4];
  const float* w_joint = (const float*)d_in[5];
  const float* b_joint = (const float*)d_in[6];
  const float* w_t1    = (const float*)d_in[7];
  const float* b_t1    = (const float*)d_in[8];
  const float* w_t2    = (const float*)d_in[9];
  const float* b_t2    = (const float*)d_in[10];
  const float* w_radar = (const float*)d_in[11];
  const float* b_radar = (const float*)d_in[12];
  const float* w_gcn   = (const float*)d_in[13];
  const float* b_gcn   = (const float*)d_in[14];
  const float* w_conv  = (const float*)d_in[15];
  const float* b_conv  = (const float*)d_in[16];
  const float* gamma   = (const float*)d_in[17];
  const float* beta    = (const float*)d_in[18];
  const float* mean    = (const float*)d_in[19];
  const float* var     = (const float*)d_in[20];
  const float* w_out   = (const float*)d_in[21];
  const float* b_out   = (const float*)d_in[22];

  char* wsb = (char*)d_ws;
  u16*   hgb   = (u16*)(wsb + OB_HGB);
  u16*   hbres = (u16*)(wsb + OB_HB);
  float* base  = (float*)(wsb + OB_BASE);
  float* s     = (float*)(wsb + OB_S);
  u16*   wtf   = (u16*)(wsb + OB_WTF);
  u16*   wgf   = (u16*)(wsb + OB_WGF);
  float* hr    = (float*)(wsb + OB_HR);
  float* bnsc  = (float*)(wsb + OB_BNSC);
  float* bnsh  = (float*)(wsb + OB_BNSH);
  float* vout  = (float*)d_out;

  hipLaunchKernelGGL(k_misc, dim3(BT_), dim3(256), 0, stream,
                     tau, w_t1, b_t1, gamma, beta, mean, var, s, bnsc, bnsh);
  hipLaunchKernelGGL(k_pack, dim3(512), dim3(64), 0, stream, w_conv, w_gcn, wtf, wgf);
  hipLaunchKernelGGL(k_hr, dim3(B_), dim3(256), 0, stream, hn, w_radar, b_radar, hr);
  hipLaunchKernelGGL(k_base, dim3(256), dim3(256), 0, stream,
                     s, z, w_t2, w_radar, b_t2, b_radar, hr, base);
  hipLaunchKernelGGL(k_hg, dim3(BT_), dim3(256), 0, stream,
                     xt, base, adj, w_joint, b_joint, hgb, hbres);
  hipLaunchKernelGGL(k_gcn2, dim3(M_ / 64), dim3(256), 0, stream,
                     wgf, b_gcn, hbres, hgb);
  hipLaunchKernelGGL(k_conv2, dim3(M_ / 64), dim3(256), 0, stream,
                     wtf, b_conv, bnsc, bnsh, w_out, b_out, hgb, vout);
}

// Round 3
// 274.641 us; speedup vs baseline: 2.8124x; 1.7120x over previous
//
#include <hip/hip_runtime.h>

typedef __attribute__((ext_vector_type(8))) short short8v;
typedef __attribute__((ext_vector_type(4))) float float4v;
typedef unsigned short u16;

constexpr int B_ = 32, T_ = 128, J_ = 24, H_ = 256;
constexpr int BT_ = B_ * T_;   // 4096
constexpr int M_  = BT_ * J_;  // 98304
constexpr float BN_EPS_ = 1e-5f, SLOPE_ = 0.2f;

// ---- workspace byte offsets ----
constexpr size_t OB_HGB  = 0;                              // bf16 [M][256] hg -> h2 (in place)
constexpr size_t OB_HB   = OB_HGB + (size_t)M_ * H_ * 2;   // bf16 [M][256] residual h
constexpr size_t OB_BASE = OB_HB  + (size_t)M_ * H_ * 2;   // f32 [BT][256]
constexpr size_t OB_S    = OB_BASE + (size_t)BT_ * H_ * 4; // f32 [BT][256]
constexpr size_t OB_WTF  = OB_S + (size_t)BT_ * H_ * 4;    // bf16 768*256 fragment-packed
constexpr size_t OB_WGF  = OB_WTF + 768 * 256 * 2;         // bf16 256*256 fragment-packed
constexpr size_t OB_HR   = OB_WGF + 256 * 256 * 2;         // f32 [32][256]
constexpr size_t OB_BNSC = OB_HR + (size_t)B_ * H_ * 4;    // f32 256
constexpr size_t OB_BNSH = OB_BNSC + 256 * 4;              // f32 256

__device__ __forceinline__ u16 f2b(float f) {
  union { float f; unsigned u; } v; v.f = f;
  return (u16)((v.u + 0x7fffu + ((v.u >> 16) & 1u)) >> 16);
}
__device__ __forceinline__ float b2f(u16 u) {
  union { unsigned u; float f; } v; v.u = ((unsigned)u) << 16; return v.f;
}

// ---------------------------------------------------------------- prep
__global__ __launch_bounds__(256) void k_misc(
    const float* __restrict__ tau, const float* __restrict__ w_t1,
    const float* __restrict__ b_t1, const float* __restrict__ gamma,
    const float* __restrict__ beta, const float* __restrict__ mean,
    const float* __restrict__ var, float* __restrict__ s,
    float* __restrict__ bnsc, float* __restrict__ bnsh) {
  int bid = blockIdx.x, tid = threadIdx.x;
  float tv = tau[bid];
  float v = tv * w_t1[tid] + b_t1[tid];
  s[bid * H_ + tid] = v / (1.f + expf(-v));
  if (bid == 0) {
    float sc = gamma[tid] * rsqrtf(var[tid] + BN_EPS_);
    bnsc[tid] = sc;
    bnsh[tid] = beta[tid] - mean[tid] * sc;
  }
}

// ---------------------------------------------------------------- pack conv/gcn weights into MFMA B-fragment order (bf16)
// frag (kb,nblk): lane l, elem j -> W[kb*32 + (l>>4)*8 + j][nblk*16 + (l&15)]
__global__ __launch_bounds__(64) void k_pack(
    const float* __restrict__ w_conv, const float* __restrict__ w_gcn,
    u16* __restrict__ wtf, u16* __restrict__ wgf) {
  int bid = blockIdx.x, l = threadIdx.x;
  int col = (l & 15), kbase = (l >> 4) * 8;
  if (bid < 384) {
    int kb = bid >> 4, nblk = bid & 15;
    int o = nblk * 16 + col;
    u16* dst = wtf + (size_t)bid * 512 + l * 8;
#pragma unroll
    for (int j = 0; j < 8; ++j) {
      int k = kb * 32 + kbase + j;
      int tap = k >> 8, i = k & 255;
      dst[j] = f2b(w_conv[o * 768 + i * 3 + tap]);
    }
  } else {
    int b2 = bid - 384;
    int kb = b2 >> 4, nblk = b2 & 15;
    int o = nblk * 16 + col;
    u16* dst = wgf + (size_t)b2 * 512 + l * 8;
#pragma unroll
    for (int j = 0; j < 8; ++j) {
      int k = kb * 32 + kbase + j;
      dst[j] = f2b(w_gcn[k * 256 + o]);
    }
  }
}

// ---------------------------------------------------------------- hr = h_n @ w_radar + b_radar
__global__ __launch_bounds__(256) void k_hr(
    const float* __restrict__ hn, const float* __restrict__ w_radar,
    const float* __restrict__ b_radar, float* __restrict__ hr) {
  __shared__ float hs[H_];
  int b = blockIdx.x, c = threadIdx.x;
  hs[c] = hn[b * H_ + c];
  __syncthreads();
  float acc = b_radar[c];
  for (int k = 0; k < H_; ++k) acc += hs[k] * w_radar[k * H_ + c];
  hr[b * H_ + c] = acc;
}

// ---------------------------------------------------------------- base = s@w_t2 + z@w_radar + biases + hr[b]  (fp32)
__global__ __launch_bounds__(256) void k_base(
    const float* __restrict__ s, const float* __restrict__ z,
    const float* __restrict__ w_t2, const float* __restrict__ w_radar,
    const float* __restrict__ b_t2, const float* __restrict__ b_radar,
    const float* __restrict__ hr, float* __restrict__ basep) {
  __shared__ float As[16][40];
  __shared__ float Bs[16][128];
  int bm = blockIdx.x & 127, bn = blockIdx.x >> 7;
  int row0 = bm * 32, col0 = bn * 128;
  int tid = threadIdx.x, ty = tid >> 5, tx = tid & 31;
  float acc[4][4] = {};
  for (int ck = 0; ck < 32; ++ck) {
    const float* A = (ck < 16) ? s : z;
    const float* W = (ck < 16) ? w_t2 : w_radar;
    int k0 = (ck & 15) * 16;
    if (tid < 128) {
      int r = tid >> 2, q = tid & 3;
      float4 v = *(const float4*)&A[(row0 + r) * H_ + k0 + q * 4];
      As[q * 4 + 0][r] = v.x; As[q * 4 + 1][r] = v.y;
      As[q * 4 + 2][r] = v.z; As[q * 4 + 3][r] = v.w;
    }
#pragma unroll
    for (int p = 0; p < 2; ++p) {
      int idx = tid + p * 256;
      int br = idx >> 5, c4 = idx & 31;
      *(float4*)&Bs[br][c4 * 4] = *(const float4*)&W[(k0 + br) * H_ + col0 + c4 * 4];
    }
    __syncthreads();
#pragma unroll
    for (int kk = 0; kk < 16; ++kk) {
      float4 av = *(const float4*)&As[kk][ty * 4];
      float4 bv = *(const float4*)&Bs[kk][tx * 4];
      float a[4] = {av.x, av.y, av.z, av.w};
      float b[4] = {bv.x, bv.y, bv.z, bv.w};
#pragma unroll
      for (int i = 0; i < 4; ++i)
#pragma unroll
        for (int j = 0; j < 4; ++j) acc[i][j] += a[i] * b[j];
    }
    __syncthreads();
  }
#pragma unroll
  for (int i = 0; i < 4; ++i) {
    int bt = row0 + ty * 4 + i;
    int b = bt >> 7;
    int c = col0 + tx * 4;
    float4 o;
    o.x = acc[i][0] + b_t2[c + 0] + b_radar[c + 0] + hr[b * H_ + c + 0];
    o.y = acc[i][1] + b_t2[c + 1] + b_radar[c + 1] + hr[b * H_ + c + 1];
    o.z = acc[i][2] + b_t2[c + 2] + b_radar[c + 2] + hr[b * H_ + c + 2];
    o.w = acc[i][3] + b_t2[c + 3] + b_radar[c + 3] + hr[b * H_ + c + 3];
    *(float4*)&basep[bt * H_ + c] = o;
  }
}

// ---------------------------------------------------------------- h (bf16) and hg = adj@h (bf16)
__global__ __launch_bounds__(256) void k_hg(
    const float* __restrict__ xt, const float* __restrict__ basep,
    const float* __restrict__ adj, const float* __restrict__ w_joint,
    const float* __restrict__ b_joint, u16* __restrict__ hgb,
    u16* __restrict__ hb) {
  __shared__ float xs[J_ * 3];
  int bt = blockIdx.x, c = threadIdx.x;
  if (c < J_ * 3) xs[c] = xt[bt * (J_ * 3) + c];
  __syncthreads();
  float wj0 = w_joint[c], wj1 = w_joint[H_ + c], wj2 = w_joint[2 * H_ + c];
  float hbase = b_joint[c] + basep[bt * H_ + c];
  float hv[J_];
#pragma unroll
  for (int j = 0; j < J_; ++j) {
    hv[j] = xs[j * 3] * wj0 + xs[j * 3 + 1] * wj1 + xs[j * 3 + 2] * wj2 + hbase;
    hb[(size_t)(bt * J_ + j) * H_ + c] = f2b(hv[j]);
  }
  float acc[J_];
#pragma unroll
  for (int j = 0; j < J_; ++j) acc[j] = 0.f;
  for (int kp = 0; kp < J_; ++kp) {
    float hvk = hv[kp];
#pragma unroll
    for (int j = 0; j < J_; ++j) acc[j] += adj[j * J_ + kp] * hvk;
  }
#pragma unroll
  for (int j = 0; j < J_; ++j) hgb[(size_t)(bt * J_ + j) * H_ + c] = f2b(acc[j]);
}

// ================================================================ barrier-free MFMA GEMMs
// A in LDS (XOR-swizzled, staged once), B frag-packed from global (L2), depth-2 reg prefetch.

#define DO_MFMA(A_, B_) do {                                              \
  _Pragma("unroll") for (int mi_ = 0; mi_ < 4; ++mi_)                     \
  _Pragma("unroll") for (int ni_ = 0; ni_ < 4; ++ni_)                     \
    acc[mi_][ni_] = __builtin_amdgcn_mfma_f32_16x16x32_bf16(              \
        A_[mi_], B_[ni_], acc[mi_][ni_], 0, 0, 0);                        \
} while (0)

// ---------------------------------------------------------------- GCN: h2 = h + relu(hg@w_gcn + b), in place over hgb
__global__ __launch_bounds__(256) void k_gcn3(
    const u16* __restrict__ wgf, const float* __restrict__ b_gcn,
    const u16* __restrict__ hb, u16* __restrict__ hgb) {
  __shared__ u16 Asm[64 * 256];  // 32 KB
  int tid = threadIdx.x;
  int l = tid & 63, wn = tid >> 6;
  int l15 = l & 15, hi16 = (l >> 4) * 16, l8 = l * 8;
  int bid = blockIdx.x;
  int swz = (bid & 7) * 192 + (bid >> 3);  // XCD-bijective (1536 = 8*192)
  int r0 = swz * 64;
  char* ab = (char*)Asm;

  // stage A (own 64 rows), swizzled
#pragma unroll
  for (int p = 0; p < 8; ++p) {
    int c = tid + p * 256;
    int lr = c >> 5, c16 = c & 31;
    short8v v = *(const short8v*)&hgb[(size_t)(r0 + lr) * 256 + c16 * 8];
    int off = (lr * 512 + c16 * 16) ^ ((lr & 7) << 4);
    *(short8v*)(ab + off) = v;
  }
  __syncthreads();

  float4v z4 = {0.f, 0.f, 0.f, 0.f};
  float4v acc[4][4];
#pragma unroll
  for (int mi = 0; mi < 4; ++mi)
#pragma unroll
    for (int ni = 0; ni < 4; ++ni) acc[mi][ni] = z4;

  const u16* wbase = wgf + (size_t)wn * 4 * 512 + l8;

#define LB_G(dst, kb) do {                                                \
  const u16* bp_ = wbase + (size_t)(kb) * 16 * 512;                       \
  _Pragma("unroll") for (int ni_ = 0; ni_ < 4; ++ni_)                     \
    dst[ni_] = *(const short8v*)(bp_ + ni_ * 512);                        \
} while (0)
#define LA_G(dst, kb) do {                                                \
  _Pragma("unroll") for (int mi_ = 0; mi_ < 4; ++mi_) {                   \
    int lr_ = mi_ * 16 + l15;                                             \
    int off_ = (lr_ * 512 + (kb) * 64 + hi16) ^ ((lr_ & 7) << 4);         \
    dst[mi_] = *(const short8v*)(ab + off_);                              \
  }                                                                       \
} while (0)

  short8v a0[4], a1[4], b0[4], b1[4];
  LB_G(b0, 0); LB_G(b1, 1); LA_G(a0, 0); LA_G(a1, 1);
#pragma unroll
  for (int kb2 = 0; kb2 < 8; kb2 += 2) {
    DO_MFMA(a0, b0);
    if (kb2 + 2 < 8) { LB_G(b0, kb2 + 2); LA_G(a0, kb2 + 2); }
    DO_MFMA(a1, b1);
    if (kb2 + 3 < 8) { LB_G(b1, kb2 + 3); LA_G(a1, kb2 + 3); }
  }
#undef LB_G
#undef LA_G

  // epilogue: h2 = h + relu(acc + b_gcn) (in-place safe: A copied to LDS, rows block-local)
  int g = l >> 4;
#pragma unroll
  for (int ni = 0; ni < 4; ++ni) {
    int col = wn * 64 + ni * 16 + l15;
    float bg = b_gcn[col];
#pragma unroll
    for (int mi = 0; mi < 4; ++mi)
#pragma unroll
      for (int r = 0; r < 4; ++r) {
        int row = r0 + mi * 16 + g * 4 + r;
        float hres = b2f(hb[(size_t)row * 256 + col]);
        float gv = acc[mi][ni][r] + bg;
        hgb[(size_t)row * 256 + col] = f2b(hres + (gv > 0.f ? gv : 0.f));
      }
  }
}

// ---------------------------------------------------------------- conv(K=3 over t) + BN + leaky + out-proj fused
__global__ __launch_bounds__(256) void k_conv3(
    const u16* __restrict__ wtf, const float* __restrict__ b_conv,
    const float* __restrict__ bnsc, const float* __restrict__ bnsh,
    const float* __restrict__ w_out, const float* __restrict__ b_out,
    const u16* __restrict__ h2b, float* __restrict__ vout) {
  __shared__ u16 Asm[112 * 256];       // 56 KB (64 rows + 24-row halo each side)
  __shared__ float pvbuf[4][64][3];    // 3 KB cross-wave reduce
  int tid = threadIdx.x;
  int l = tid & 63, wn = tid >> 6;
  int l15 = l & 15, hi16 = (l >> 4) * 16, l8 = l * 8;
  int bid = blockIdx.x;
  int swz = (bid & 7) * 192 + (bid >> 3);
  int r0 = swz * 64;
  char* ab = (char*)Asm;

  // stage A rows [r0-24, r0+88), swizzled; clamp OOB (values masked later)
#pragma unroll
  for (int p = 0; p < 14; ++p) {
    int c = tid + p * 256;
    int lr = c >> 5, c16 = c & 31;
    int grow = r0 - 24 + lr;
    grow = grow < 0 ? 0 : (grow >= M_ ? M_ - 1 : grow);
    short8v v = *(const short8v*)&h2b[(size_t)grow * 256 + c16 * 8];
    int off = (lr * 512 + c16 * 16) ^ ((lr & 7) << 4);
    *(short8v*)(ab + off) = v;
  }
  __syncthreads();

  int t0[4];
#pragma unroll
  for (int mi = 0; mi < 4; ++mi) {
    int row = r0 + mi * 16 + l15;
    t0[mi] = (row / 24) & 127;
  }
  short8v z8 = {0, 0, 0, 0, 0, 0, 0, 0};

  float4v z4 = {0.f, 0.f, 0.f, 0.f};
  float4v acc[4][4];
#pragma unroll
  for (int mi = 0; mi < 4; ++mi)
#pragma unroll
    for (int ni = 0; ni < 4; ++ni) acc[mi][ni] = z4;

  const u16* wbase = wtf + (size_t)wn * 4 * 512 + l8;

#define LB_C(dst, kb) do {                                                \
  const u16* bp_ = wbase + (size_t)(kb) * 16 * 512;                       \
  _Pragma("unroll") for (int ni_ = 0; ni_ < 4; ++ni_)                     \
    dst[ni_] = *(const short8v*)(bp_ + ni_ * 512);                        \
} while (0)
#define LA_C(dst, kb) do {                                                \
  int tap_ = (kb) >> 3;                                                   \
  _Pragma("unroll") for (int mi_ = 0; mi_ < 4; ++mi_) {                   \
    int lr_ = tap_ * 24 + mi_ * 16 + l15;                                 \
    int off_ = (lr_ * 512 + ((kb) & 7) * 64 + hi16) ^ ((lr_ & 7) << 4);   \
    short8v v_ = *(const short8v*)(ab + off_);                            \
    if (tap_ != 1) {                                                      \
      bool ok_ = (unsigned)(t0[mi_] + tap_ - 1) < 128u;                   \
      v_ = ok_ ? v_ : z8;                                                 \
    }                                                                     \
    dst[mi_] = v_;                                                        \
  }                                                                       \
} while (0)

  short8v a0[4], a1[4], b0[4], b1[4];
  LB_C(b0, 0); LB_C(b1, 1); LA_C(a0, 0); LA_C(a1, 1);
#pragma unroll
  for (int kb2 = 0; kb2 < 24; kb2 += 2) {
    DO_MFMA(a0, b0);
    if (kb2 + 2 < 24) { LB_C(b0, kb2 + 2); LA_C(a0, kb2 + 2); }
    DO_MFMA(a1, b1);
    if (kb2 + 3 < 24) { LB_C(b1, kb2 + 3); LA_C(a1, kb2 + 3); }
  }
#undef LB_C
#undef LA_C

  // epilogue: bias + BN + leaky, project to 3, reduce over this wave's 64 cols
  float pv[4][4][3] = {};
#pragma unroll
  for (int ni = 0; ni < 4; ++ni) {
    int col = wn * 64 + ni * 16 + l15;
    float bc = b_conv[col], scv = bnsc[col], shv = bnsh[col];
    float w0v = w_out[col * 3], w1v = w_out[col * 3 + 1], w2v = w_out[col * 3 + 2];
#pragma unroll
    for (int mi = 0; mi < 4; ++mi)
#pragma unroll
      for (int r = 0; r < 4; ++r) {
        float hv = acc[mi][ni][r] + bc;
        hv = hv * scv + shv;
        hv = (hv >= 0.f) ? hv : SLOPE_ * hv;
        pv[mi][r][0] += hv * w0v;
        pv[mi][r][1] += hv * w1v;
        pv[mi][r][2] += hv * w2v;
      }
  }
#pragma unroll
  for (int mi = 0; mi < 4; ++mi)
#pragma unroll
    for (int r = 0; r < 4; ++r)
#pragma unroll
      for (int c = 0; c < 3; ++c) {
        float v = pv[mi][r][c];
        v += __shfl_xor(v, 1);
        v += __shfl_xor(v, 2);
        v += __shfl_xor(v, 4);
        v += __shfl_xor(v, 8);
        pv[mi][r][c] = v;
      }
  int g = l >> 4;
  if (l15 == 0) {
#pragma unroll
    for (int mi = 0; mi < 4; ++mi)
#pragma unroll
      for (int r = 0; r < 4; ++r) {
        int rl = mi * 16 + g * 4 + r;
        pvbuf[wn][rl][0] = pv[mi][r][0];
        pvbuf[wn][rl][1] = pv[mi][r][1];
        pvbuf[wn][rl][2] = pv[mi][r][2];
      }
  }
  __syncthreads();
  if (tid < 192) {
    int row = tid / 3, c = tid - row * 3;
    float sum = pvbuf[0][row][c] + pvbuf[1][row][c] + pvbuf[2][row][c] +
                pvbuf[3][row][c] + b_out[c];
    vout[(size_t)(r0 + row) * 3 + c] = sum;
  }
}

extern "C" void kernel_launch(void* const* d_in, const int* in_sizes, int n_in,
                              void* d_out, int out_size, void* d_ws, size_t ws_size,
                              hipStream_t stream) {
  (void)in_sizes; (void)n_in; (void)out_size; (void)ws_size;
  const float* xt      = (const float*)d_in[0];
  const float* tau     = (const float*)d_in[1];
  const float* z       = (const float*)d_in[2];
  const float* hn      = (const float*)d_in[3];
  const float* adj     = (const float*)d_in[4];
  const float* w_joint = (const float*)d_in[5];
  const float* b_joint = (const float*)d_in[6];
  const float* w_t1    = (const float*)d_in[7];
  const float* b_t1    = (const float*)d_in[8];
  const float* w_t2    = (const float*)d_in[9];
  const float* b_t2    = (const float*)d_in[10];
  const float* w_radar = (const float*)d_in[11];
  const float* b_radar = (const float*)d_in[12];
  const float* w_gcn   = (const float*)d_in[13];
  const float* b_gcn   = (const float*)d_in[14];
  const float* w_conv  = (const float*)d_in[15];
  const float* b_conv  = (const float*)d_in[16];
  const float* gamma   = (const float*)d_in[17];
  const float* beta    = (const float*)d_in[18];
  const float* mean    = (const float*)d_in[19];
  const float* var     = (const float*)d_in[20];
  const float* w_out   = (const float*)d_in[21];
  const float* b_out   = (const float*)d_in[22];

  char* wsb = (char*)d_ws;
  u16*   hgb   = (u16*)(wsb + OB_HGB);
  u16*   hbres = (u16*)(wsb + OB_HB);
  float* base  = (float*)(wsb + OB_BASE);
  float* s     = (float*)(wsb + OB_S);
  u16*   wtf   = (u16*)(wsb + OB_WTF);
  u16*   wgf   = (u16*)(wsb + OB_WGF);
  float* hr    = (float*)(wsb + OB_HR);
  float* bnsc  = (float*)(wsb + OB_BNSC);
  float* bnsh  = (float*)(wsb + OB_BNSH);
  float* vout  = (float*)d_out;

  hipLaunchKernelGGL(k_misc, dim3(BT_), dim3(256), 0, stream,
                     tau, w_t1, b_t1, gamma, beta, mean, var, s, bnsc, bnsh);
  hipLaunchKernelGGL(k_pack, dim3(512), dim3(64), 0, stream, w_conv, w_gcn, wtf, wgf);
  hipLaunchKernelGGL(k_hr, dim3(B_), dim3(256), 0, stream, hn, w_radar, b_radar, hr);
  hipLaunchKernelGGL(k_base, dim3(256), dim3(256), 0, stream,
                     s, z, w_t2, w_radar, b_t2, b_radar, hr, base);
  hipLaunchKernelGGL(k_hg, dim3(BT_), dim3(256), 0, stream,
                     xt, base, adj, w_joint, b_joint, hgb, hbres);
  hipLaunchKernelGGL(k_gcn3, dim3(M_ / 64), dim3(256), 0, stream,
                     wgf, b_gcn, hbres, hgb);
  hipLaunchKernelGGL(k_conv3, dim3(M_ / 64), dim3(256), 0, stream,
                     wtf, b_conv, bnsc, bnsh, w_out, b_out, hgb, vout);
}